// Round 3
// baseline (1865.981 us; speedup 1.0000x reference)
//
#include <hip/hip_runtime.h>
#include <hip/hip_bf16.h>

#define TOKENS 2048
#define HDIM   2048
#define IDIM   5632
#define NEXP   8
#define NSLOT  (TOKENS * 2)
#define BM 128
#define BN 128
#define BK 32   /* fallback kernels */

typedef __attribute__((ext_vector_type(8))) short bf16x8;
typedef __attribute__((ext_vector_type(4))) float f32x4;

__device__ __forceinline__ unsigned short f2bf(float f) {
    union { float f; unsigned u; } v; v.f = f;
    unsigned r = v.u + 0x7FFFu + ((v.u >> 16) & 1u);   // RNE to bf16
    return (unsigned short)(r >> 16);
}
// packed f32x2 -> bf16x2 (compiler emits v_cvt_pk_bf16_f32, RNE)
__device__ __forceinline__ unsigned pack2(float lo, float hi) {
    float2 f; f.x = lo; f.y = hi;
    __hip_bfloat162 h = __float22bfloat162_rn(f);
    union { __hip_bfloat162 h; unsigned u; } c; c.h = h;
    return c.u;
}
// load 8 contiguous fp32, convert to 8 bf16, write 16B to LDS (fragment-order chunk)
__device__ __forceinline__ void stage_b_chunk(const float* __restrict__ p, unsigned short* dst) {
    float4 lo = *(const float4*)(p);
    float4 hi = *(const float4*)(p + 4);
    uint4 v;
    v.x = pack2(lo.x, lo.y);
    v.y = pack2(lo.z, lo.w);
    v.z = pack2(hi.x, hi.y);
    v.w = pack2(hi.z, hi.w);
    *(uint4*)dst = v;
}
// async global->LDS, 16B per lane: LDS dest = wave-uniform base + lane*16
__device__ __forceinline__ void gl2lds16(const void* g, void* l) {
    __builtin_amdgcn_global_load_lds(
        (const __attribute__((address_space(1))) unsigned int*)g,
        (__attribute__((address_space(3))) unsigned int*)l,
        16, 0, 0);
}

// ---------------- K0: zero output (fallback path only) ----------------
__global__ __launch_bounds__(256) void k_zero(float* __restrict__ out) {
    int i = blockIdx.x * 256 + threadIdx.x;
    float4 z = {0.f, 0.f, 0.f, 0.f};
    ((float4*)out)[i] = z;
}

// ---------------- K1: gate logits + sparsemixer routing ----------------
__global__ __launch_bounds__(256) void k_gate(const float* __restrict__ x,
                                              const float* __restrict__ gw,
                                              int* __restrict__ sel,
                                              float* __restrict__ wts) {
    int wave = threadIdx.x >> 6, lane = threadIdx.x & 63;
    int t = blockIdx.x * 4 + wave;
    const float4* xr = (const float4*)(x + (size_t)t * HDIM);
    const float4* g  = (const float4*)gw;
    float acc[NEXP];
#pragma unroll
    for (int e = 0; e < NEXP; e++) acc[e] = 0.f;
#pragma unroll
    for (int it = 0; it < HDIM / 4 / 64; ++it) {   // 8 iters
        int idx = it * 64 + lane;
        float4 xv = xr[idx];
#pragma unroll
        for (int e = 0; e < NEXP; e++) {
            float4 gv = g[e * (HDIM / 4) + idx];
            acc[e] += xv.x * gv.x + xv.y * gv.y + xv.z * gv.z + xv.w * gv.w;
        }
    }
#pragma unroll
    for (int e = 0; e < NEXP; e++) {
        float v = acc[e];
#pragma unroll
        for (int off = 32; off > 0; off >>= 1) v += __shfl_xor(v, off, 64);
        acc[e] = v;
    }
    if (lane == 0) {
        float s[NEXP];
#pragma unroll
        for (int e = 0; e < NEXP; e++) s[e] = acc[e];
        float m1 = s[0]; int i1 = 0;
#pragma unroll
        for (int e = 1; e < NEXP; e++) if (s[e] > m1) { m1 = s[e]; i1 = e; }
        float m2 = -3.0e38f; int i2 = 0;
#pragma unroll
        for (int e = 0; e < NEXP; e++) if (e != i1 && s[e] > m2) { m2 = s[e]; i2 = e; }
        float sum1 = 0.f;
#pragma unroll
        for (int e = 0; e < NEXP; e++) {
            float f = fmaxf(fabsf(s[e]), m1);
            bool masked = ((m1 - s[e]) / f) > 0.02f;
            if (!masked) sum1 += expf(s[e] - m1);
        }
        float sum2 = 0.f;
#pragma unroll
        for (int e = 0; e < NEXP; e++) {
            if (e == i1) continue;
            float f = fmaxf(fabsf(s[e]), m2);
            bool masked = ((m2 - s[e]) / f) > 0.02f;
            if (!masked) sum2 += expf(s[e] - m2);
        }
        sel[2 * t]     = i1;
        sel[2 * t + 1] = i2;
        wts[2 * t]     = 1.f / sum1;
        wts[2 * t + 1] = 1.f / sum2;
    }
}

// ---------------- K2: histogram + exclusive prefix ----------------
__global__ __launch_bounds__(256) void k_hist(const int* __restrict__ sel,
                                              int* __restrict__ cnt,
                                              int* __restrict__ offs,
                                              int* __restrict__ cursor) {
    __shared__ int c_s[NEXP];
    int tid = threadIdx.x;
    if (tid < NEXP) c_s[tid] = 0;
    __syncthreads();
    for (int i = tid; i < NSLOT; i += 256) atomicAdd(&c_s[sel[i]], 1);
    __syncthreads();
    if (tid == 0) {
        int o = 0;
        for (int e = 0; e < NEXP; e++) { cnt[e] = c_s[e]; offs[e] = o; o += c_s[e]; cursor[e] = 0; }
    }
}

// ---------------- K3: slot assignment + gather x rows to bf16 ----------------
__global__ __launch_bounds__(256) void k_gather(const float* __restrict__ x,
                                                const int* __restrict__ sel,
                                                const float* __restrict__ wts,
                                                const int* __restrict__ offs,
                                                int* __restrict__ cursor,
                                                int* __restrict__ rowtok,
                                                float* __restrict__ roww,
                                                int* __restrict__ tokslot,
                                                unsigned short* __restrict__ Xe) {
    int t = blockIdx.x;
    __shared__ int slot_s[2];
    if (threadIdx.x == 0) {
        int s0 = sel[2 * t], s1 = sel[2 * t + 1];
        int p0 = offs[s0] + atomicAdd(&cursor[s0], 1);
        int p1 = offs[s1] + atomicAdd(&cursor[s1], 1);
        rowtok[p0] = t; roww[p0] = wts[2 * t];
        rowtok[p1] = t; roww[p1] = wts[2 * t + 1];
        tokslot[2 * t] = p0; tokslot[2 * t + 1] = p1;
        slot_s[0] = p0; slot_s[1] = p1;
    }
    __syncthreads();
    int p0 = slot_s[0], p1 = slot_s[1];
    int base = threadIdx.x * 8;                     // 8 elems/thread, 2048 total
    const float* xp = x + (size_t)t * HDIM + base;
    float4 a = *(const float4*)(xp);
    float4 b = *(const float4*)(xp + 4);
    uint4 v;
    v.x = pack2(a.x, a.y); v.y = pack2(a.z, a.w);
    v.z = pack2(b.x, b.y); v.w = pack2(b.z, b.w);
    *(uint4*)(Xe + (size_t)p0 * HDIM + base) = v;
    *(uint4*)(Xe + (size_t)p1 * HDIM + base) = v;
}

// ==================== FAST PATH (direct fp32 weight staging, BK=64) ====================
// A-tiles (bf16: Xe / hid) via global_load_lds; B-tiles (fp32 weights) via
// reg-staging + v_cvt_pk_bf16_f32 (compiler-emitted from __float22bfloat162_rn).
// No weight pre-conversion kernels, no bf16 weight round-trip through HBM.

// ---------------- K4: stage-1 grouped GEMM: hid = silu(X@w1^T) * (X@w3^T) ----------------
__global__ __launch_bounds__(256, 2) void k_ffn1_bf(const unsigned short* __restrict__ Xe,
                                                    const float* __restrict__ w1,
                                                    const float* __restrict__ w3,
                                                    const int* __restrict__ cnt,
                                                    const int* __restrict__ offs,
                                                    unsigned short* __restrict__ hid) {
    int e = blockIdx.z;
    int c = cnt[e];
    int bm = blockIdx.y;
    if (bm * BM >= c) return;
    int n0 = blockIdx.x * BN;
    int row0 = offs[e] + bm * BM;
    int rows_here = c - bm * BM;
    const float* W1 = w1 + (size_t)e * IDIM * HDIM;
    const float* W3 = w3 + (size_t)e * IDIM * HDIM;

    // BK=64: two 32-wide k-halves, fragment-order chunks, 16 KB per buffer
    __shared__ __align__(16) unsigned short As[16 * 512];
    __shared__ __align__(16) unsigned short B1s[16 * 512];
    __shared__ __align__(16) unsigned short B3s[16 * 512];

    int tid = threadIdx.x, lane = tid & 63, wave = tid >> 6;
    int wm = wave >> 1, wn = wave & 1;
    int fr = lane & 15, kq = lane >> 4;
    int lo8 = lane * 8;

    f32x4 acc1[4][4], acc3[4][4];
    f32x4 z = {0.f, 0.f, 0.f, 0.f};
#pragma unroll
    for (int i = 0; i < 4; i++)
#pragma unroll
        for (int j = 0; j < 4; j++) { acc1[i][j] = z; acc3[i][j] = z; }

    int ar0 = min(row0 + wave * 16 + fr, NSLOT - 1);
    int ar1 = min(row0 + (wave + 4) * 16 + fr, NSLOT - 1);
    const unsigned short* aP0 = Xe + (size_t)ar0 * HDIM + kq * 8;
    const unsigned short* aP1 = Xe + (size_t)ar1 * HDIM + kq * 8;
    const float* b1P0 = W1 + (size_t)(n0 + wave * 16 + fr) * HDIM + kq * 8;
    const float* b1P1 = W1 + (size_t)(n0 + (wave + 4) * 16 + fr) * HDIM + kq * 8;
    const float* b3P0 = W3 + (size_t)(n0 + wave * 16 + fr) * HDIM + kq * 8;
    const float* b3P1 = W3 + (size_t)(n0 + (wave + 4) * 16 + fr) * HDIM + kq * 8;

    unsigned short* aL0  = As  + wave * 512;                  // wave-uniform (gl2lds)
    unsigned short* aL1  = As  + (wave + 4) * 512;
    unsigned short* b1D0 = B1s + wave * 512 + lo8;            // per-lane (ds_write)
    unsigned short* b1D1 = B1s + (wave + 4) * 512 + lo8;
    unsigned short* b3D0 = B3s + wave * 512 + lo8;
    unsigned short* b3D1 = B3s + (wave + 4) * 512 + lo8;

    for (int k0 = 0; k0 < HDIM; k0 += 64) {
        __syncthreads();
        // async A staging (bf16, direct to LDS)
        gl2lds16(aP0 + k0, aL0);
        gl2lds16(aP1 + k0, aL1);
        gl2lds16(aP0 + k0 + 32, aL0 + 4096);
        gl2lds16(aP1 + k0 + 32, aL1 + 4096);
        // B staging: fp32 -> cvt_pk -> LDS (8 chunks of 8 elems per thread)
        stage_b_chunk(b1P0 + k0,      b1D0);
        stage_b_chunk(b1P1 + k0,      b1D1);
        stage_b_chunk(b1P0 + k0 + 32, b1D0 + 4096);
        stage_b_chunk(b1P1 + k0 + 32, b1D1 + 4096);
        stage_b_chunk(b3P0 + k0,      b3D0);
        stage_b_chunk(b3P1 + k0,      b3D1);
        stage_b_chunk(b3P0 + k0 + 32, b3D0 + 4096);
        stage_b_chunk(b3P1 + k0 + 32, b3D1 + 4096);
        __syncthreads();   // drains vmcnt (A) + lgkmcnt (B writes)
#pragma unroll
        for (int h = 0; h < 2; h++) {
            int hb = h * 4096;
            bf16x8 af[4];
#pragma unroll
            for (int i = 0; i < 4; i++)
                af[i] = *(const bf16x8*)&As[hb + ((wm * 4 + i) * 64 + lane) * 8];
#pragma unroll
            for (int j = 0; j < 4; j++) {
                bf16x8 b1f = *(const bf16x8*)&B1s[hb + ((wn * 4 + j) * 64 + lane) * 8];
                bf16x8 b3f = *(const bf16x8*)&B3s[hb + ((wn * 4 + j) * 64 + lane) * 8];
#pragma unroll
                for (int i = 0; i < 4; i++) {
                    acc1[i][j] = __builtin_amdgcn_mfma_f32_16x16x32_bf16(af[i], b1f, acc1[i][j], 0, 0, 0);
                    acc3[i][j] = __builtin_amdgcn_mfma_f32_16x16x32_bf16(af[i], b3f, acc3[i][j], 0, 0, 0);
                }
            }
        }
    }
    // epilogue: C/D layout col=lane&15, row=(lane>>4)*4+reg
    int qr = (lane >> 4) * 4, cb = lane & 15;
#pragma unroll
    for (int i = 0; i < 4; i++) {
        int rl = wm * 64 + i * 16 + qr;
#pragma unroll
        for (int v = 0; v < 4; v++) {
            int r = rl + v;
            if (r < rows_here) {
                size_t rowoff = (size_t)(row0 + r) * IDIM;
#pragma unroll
                for (int j = 0; j < 4; j++) {
                    float u1 = acc1[i][j][v], u3 = acc3[i][j][v];
                    float h = u1 * u3 / (1.f + __expf(-u1));   // silu(u1)*u3
                    hid[rowoff + n0 + wn * 64 + j * 16 + cb] = f2bf(h);
                }
            }
        }
    }
}

// ---------------- K5: stage-2 grouped GEMM: Oslot = w * (hid @ w2^T), no atomics, BK=64 ----------------
__global__ __launch_bounds__(256, 2) void k_ffn2_bf(const unsigned short* __restrict__ hid,
                                                    const float* __restrict__ w2,
                                                    const int* __restrict__ cnt,
                                                    const int* __restrict__ offs,
                                                    const float* __restrict__ roww,
                                                    float* __restrict__ Oslot) {
    int e = blockIdx.z;
    int c = cnt[e];
    int bm = blockIdx.y;
    if (bm * BM >= c) return;
    int n0 = blockIdx.x * BN;
    int row0 = offs[e] + bm * BM;
    int rows_here = c - bm * BM;
    const float* W2 = w2 + (size_t)e * HDIM * IDIM;

    __shared__ __align__(16) unsigned short As[16 * 512];
    __shared__ __align__(16) unsigned short Bs[16 * 512];
    __shared__ float w_s[BM];

    int tid = threadIdx.x, lane = tid & 63, wave = tid >> 6;
    int wm = wave >> 1, wn = wave & 1;
    int fr = lane & 15, kq = lane >> 4;
    int lo8 = lane * 8;

    if (tid < BM) w_s[tid] = (tid < rows_here) ? roww[row0 + tid] : 0.f;

    f32x4 acc[4][4];
    f32x4 z = {0.f, 0.f, 0.f, 0.f};
#pragma unroll
    for (int i = 0; i < 4; i++)
#pragma unroll
        for (int j = 0; j < 4; j++) acc[i][j] = z;

    int ar0 = min(row0 + wave * 16 + fr, NSLOT - 1);
    int ar1 = min(row0 + (wave + 4) * 16 + fr, NSLOT - 1);
    const unsigned short* aP0 = hid + (size_t)ar0 * IDIM + kq * 8;
    const unsigned short* aP1 = hid + (size_t)ar1 * IDIM + kq * 8;
    const float* bP0 = W2 + (size_t)(n0 + wave * 16 + fr) * IDIM + kq * 8;
    const float* bP1 = W2 + (size_t)(n0 + (wave + 4) * 16 + fr) * IDIM + kq * 8;

    unsigned short* aL0 = As + wave * 512;
    unsigned short* aL1 = As + (wave + 4) * 512;
    unsigned short* bD0 = Bs + wave * 512 + lo8;
    unsigned short* bD1 = Bs + (wave + 4) * 512 + lo8;

    for (int k0 = 0; k0 < IDIM; k0 += 64) {
        __syncthreads();
        gl2lds16(aP0 + k0, aL0);
        gl2lds16(aP1 + k0, aL1);
        gl2lds16(aP0 + k0 + 32, aL0 + 4096);
        gl2lds16(aP1 + k0 + 32, aL1 + 4096);
        stage_b_chunk(bP0 + k0,      bD0);
        stage_b_chunk(bP1 + k0,      bD1);
        stage_b_chunk(bP0 + k0 + 32, bD0 + 4096);
        stage_b_chunk(bP1 + k0 + 32, bD1 + 4096);
        __syncthreads();
#pragma unroll
        for (int h = 0; h < 2; h++) {
            int hb = h * 4096;
            bf16x8 af[4];
#pragma unroll
            for (int i = 0; i < 4; i++)
                af[i] = *(const bf16x8*)&As[hb + ((wm * 4 + i) * 64 + lane) * 8];
#pragma unroll
            for (int j = 0; j < 4; j++) {
                bf16x8 bf = *(const bf16x8*)&Bs[hb + ((wn * 4 + j) * 64 + lane) * 8];
#pragma unroll
                for (int i = 0; i < 4; i++)
                    acc[i][j] = __builtin_amdgcn_mfma_f32_16x16x32_bf16(af[i], bf, acc[i][j], 0, 0, 0);
            }
        }
    }
    int qr = (lane >> 4) * 4, cb = lane & 15;
#pragma unroll
    for (int i = 0; i < 4; i++) {
        int rl = wm * 64 + i * 16 + qr;
#pragma unroll
        for (int v = 0; v < 4; v++) {
            int r = rl + v;
            if (r < rows_here) {
                float wgt = w_s[r];
                float* orow = Oslot + (size_t)(row0 + r) * HDIM + n0 + wn * 64 + cb;
#pragma unroll
                for (int j = 0; j < 4; j++)
                    orow[j * 16] = acc[i][j][v] * wgt;
            }
        }
    }
}

// ---------------- K6: combine the two expert rows per token ----------------
__global__ __launch_bounds__(256) void k_combine(const float* __restrict__ Oslot,
                                                 const int* __restrict__ tokslot,
                                                 float* __restrict__ out) {
    int t = blockIdx.x;
    int p0 = tokslot[2 * t], p1 = tokslot[2 * t + 1];
    int i = threadIdx.x * 8;
    const float4* r0 = (const float4*)(Oslot + (size_t)p0 * HDIM + i);
    const float4* r1 = (const float4*)(Oslot + (size_t)p1 * HDIM + i);
    float4 a0 = r0[0], b0 = r0[1], a1 = r1[0], b1 = r1[1];
    float4 o0 = {a0.x + a1.x, a0.y + a1.y, a0.z + a1.z, a0.w + a1.w};
    float4 o1 = {b0.x + b1.x, b0.y + b1.y, b0.z + b1.z, b0.w + b1.w};
    float* op = out + (size_t)t * HDIM + i;
    *(float4*)op = o0;
    *(float4*)(op + 4) = o1;
}

// ==================== FALLBACK PATH (fp32 weights, convert-at-stage, BK=32) ====================

__global__ __launch_bounds__(256, 2) void k_ffn1_cv(const unsigned short* __restrict__ Xe,
                                                    const float* __restrict__ w1,
                                                    const float* __restrict__ w3,
                                                    const int* __restrict__ cnt,
                                                    const int* __restrict__ offs,
                                                    unsigned short* __restrict__ hid) {
    int e = blockIdx.z;
    int c = cnt[e];
    int bm = blockIdx.y;
    if (bm * BM >= c) return;
    int n0 = blockIdx.x * BN;
    int row0 = offs[e] + bm * BM;
    int rows_here = c - bm * BM;
    const float* W1 = w1 + (size_t)e * IDIM * HDIM;
    const float* W3 = w3 + (size_t)e * IDIM * HDIM;

    __shared__ __align__(16) unsigned short As[8 * 512];
    __shared__ __align__(16) unsigned short B1s[8 * 512];
    __shared__ __align__(16) unsigned short B3s[8 * 512];

    int tid = threadIdx.x, lane = tid & 63, wave = tid >> 6;
    int wm = wave >> 1, wn = wave & 1;
    int fr = lane & 15, kq = lane >> 4;

    f32x4 acc1[4][4], acc3[4][4];
    f32x4 z = {0.f, 0.f, 0.f, 0.f};
#pragma unroll
    for (int i = 0; i < 4; i++)
#pragma unroll
        for (int j = 0; j < 4; j++) { acc1[i][j] = z; acc3[i][j] = z; }

    int ar0 = min(row0 + wave * 16 + fr, NSLOT - 1);
    int ar1 = min(row0 + (wave + 4) * 16 + fr, NSLOT - 1);
    const unsigned short* aP0 = Xe + (size_t)ar0 * HDIM + kq * 8;
    const unsigned short* aP1 = Xe + (size_t)ar1 * HDIM + kq * 8;
    const float* b1P0 = W1 + (size_t)(n0 + wave * 16 + fr) * HDIM + kq * 8;
    const float* b1P1 = W1 + (size_t)(n0 + (wave + 4) * 16 + fr) * HDIM + kq * 8;
    const float* b3P0 = W3 + (size_t)(n0 + wave * 16 + fr) * HDIM + kq * 8;
    const float* b3P1 = W3 + (size_t)(n0 + (wave + 4) * 16 + fr) * HDIM + kq * 8;

    for (int k0 = 0; k0 < HDIM; k0 += BK) {
        __syncthreads();
        *(uint4*)&As[(size_t)tid * 8]         = *(const uint4*)(aP0 + k0);
        *(uint4*)&As[(size_t)(tid + 256) * 8] = *(const uint4*)(aP1 + k0);
        stage_b_chunk(b1P0 + k0, &B1s[(size_t)tid * 8]);
        stage_b_chunk(b1P1 + k0, &B1s[(size_t)(tid + 256) * 8]);
        stage_b_chunk(b3P0 + k0, &B3s[(size_t)tid * 8]);
        stage_b_chunk(b3P1 + k0, &B3s[(size_t)(tid + 256) * 8]);
        __syncthreads();
        bf16x8 af[4];
#pragma unroll
        for (int i = 0; i < 4; i++)
            af[i] = *(const bf16x8*)&As[((wm * 4 + i) * 64 + lane) * 8];
#pragma unroll
        for (int j = 0; j < 4; j++) {
            bf16x8 b1f = *(const bf16x8*)&B1s[((wn * 4 + j) * 64 + lane) * 8];
            bf16x8 b3f = *(const bf16x8*)&B3s[((wn * 4 + j) * 64 + lane) * 8];
#pragma unroll
            for (int i = 0; i < 4; i++) {
                acc1[i][j] = __builtin_amdgcn_mfma_f32_16x16x32_bf16(af[i], b1f, acc1[i][j], 0, 0, 0);
                acc3[i][j] = __builtin_amdgcn_mfma_f32_16x16x32_bf16(af[i], b3f, acc3[i][j], 0, 0, 0);
            }
        }
    }
    int qr = (lane >> 4) * 4, cb = lane & 15;
#pragma unroll
    for (int i = 0; i < 4; i++) {
        int rl = wm * 64 + i * 16 + qr;
#pragma unroll
        for (int v = 0; v < 4; v++) {
            int r = rl + v;
            if (r < rows_here) {
                size_t rowoff = (size_t)(row0 + r) * IDIM;
#pragma unroll
                for (int j = 0; j < 4; j++) {
                    float u1 = acc1[i][j][v], u3 = acc3[i][j][v];
                    float h = u1 * u3 / (1.f + __expf(-u1));
                    hid[rowoff + n0 + wn * 64 + j * 16 + cb] = f2bf(h);
                }
            }
        }
    }
}

__global__ __launch_bounds__(256, 2) void k_ffn2_cv(const unsigned short* __restrict__ hid,
                                                    const float* __restrict__ w2,
                                                    const int* __restrict__ cnt,
                                                    const int* __restrict__ offs,
                                                    const int* __restrict__ rowtok,
                                                    const float* __restrict__ roww,
                                                    float* __restrict__ out) {
    int e = blockIdx.z;
    int c = cnt[e];
    int bm = blockIdx.y;
    if (bm * BM >= c) return;
    int n0 = blockIdx.x * BN;
    int row0 = offs[e] + bm * BM;
    int rows_here = c - bm * BM;
    const float* W2 = w2 + (size_t)e * HDIM * IDIM;

    __shared__ __align__(16) unsigned short As[8 * 512];
    __shared__ __align__(16) unsigned short Bs[8 * 512];
    __shared__ int   tok_s[BM];
    __shared__ float w_s[BM];

    int tid = threadIdx.x, lane = tid & 63, wave = tid >> 6;
    int wm = wave >> 1, wn = wave & 1;
    int fr = lane & 15, kq = lane >> 4;

    if (tid < BM) {
        bool valid = (tid < rows_here);
        tok_s[tid] = valid ? rowtok[row0 + tid] : 0;
        w_s[tid]   = valid ? roww[row0 + tid] : 0.f;
    }

    f32x4 acc[4][4];
    f32x4 z = {0.f, 0.f, 0.f, 0.f};
#pragma unroll
    for (int i = 0; i < 4; i++)
#pragma unroll
        for (int j = 0; j < 4; j++) acc[i][j] = z;

    int ar0 = min(row0 + wave * 16 + fr, NSLOT - 1);
    int ar1 = min(row0 + (wave + 4) * 16 + fr, NSLOT - 1);
    const unsigned short* aP0 = hid + (size_t)ar0 * IDIM + kq * 8;
    const unsigned short* aP1 = hid + (size_t)ar1 * IDIM + kq * 8;
    const float* bP0 = W2 + (size_t)(n0 + wave * 16 + fr) * IDIM + kq * 8;
    const float* bP1 = W2 + (size_t)(n0 + (wave + 4) * 16 + fr) * IDIM + kq * 8;

    for (int k0 = 0; k0 < IDIM; k0 += BK) {
        __syncthreads();
        *(uint4*)&As[(size_t)tid * 8]         = *(const uint4*)(aP0 + k0);
        *(uint4*)&As[(size_t)(tid + 256) * 8] = *(const uint4*)(aP1 + k0);
        stage_b_chunk(bP0 + k0, &Bs[(size_t)tid * 8]);
        stage_b_chunk(bP1 + k0, &Bs[(size_t)(tid + 256) * 8]);
        __syncthreads();
        bf16x8 af[4];
#pragma unroll
        for (int i = 0; i < 4; i++)
            af[i] = *(const bf16x8*)&As[((wm * 4 + i) * 64 + lane) * 8];
#pragma unroll
        for (int j = 0; j < 4; j++) {
            bf16x8 bf = *(const bf16x8*)&Bs[((wn * 4 + j) * 64 + lane) * 8];
#pragma unroll
            for (int i = 0; i < 4; i++)
                acc[i][j] = __builtin_amdgcn_mfma_f32_16x16x32_bf16(af[i], bf, acc[i][j], 0, 0, 0);
        }
    }
    int qr = (lane >> 4) * 4, cb = lane & 15;
#pragma unroll
    for (int i = 0; i < 4; i++) {
        int rl = wm * 64 + i * 16 + qr;
#pragma unroll
        for (int v = 0; v < 4; v++) {
            int r = rl + v;
            if (r < rows_here) {
                int tok = tok_s[r];
                float wgt = w_s[r];
                float* orow = out + (size_t)tok * HDIM + n0 + wn * 64 + cb;
#pragma unroll
                for (int j = 0; j < 4; j++)
                    atomicAdd(orow + j * 16, acc[i][j][v] * wgt);
            }
        }
    }
}

extern "C" void kernel_launch(void* const* d_in, const int* in_sizes, int n_in,
                              void* d_out, int out_size, void* d_ws, size_t ws_size,
                              hipStream_t stream) {
    const float* x  = (const float*)d_in[0];
    const float* gw = (const float*)d_in[1];
    const float* w1 = (const float*)d_in[2];
    const float* w2 = (const float*)d_in[3];
    const float* w3 = (const float*)d_in[4];
    float* out = (float*)d_out;

    char* ws = (char*)d_ws;
    int*   sel     = (int*)(ws);                   // 4096 ints
    float* wts     = (float*)(ws + 16 * 1024);     // 4096 floats
    int*   cnt     = (int*)(ws + 32 * 1024);       // 8
    int*   offs    = (int*)(ws + 32 * 1024 + 256); // 8
    int*   cursor  = (int*)(ws + 32 * 1024 + 512); // 8
    int*   rowtok  = (int*)(ws + 48 * 1024);       // 4096
    float* roww    = (float*)(ws + 64 * 1024);     // 4096
    int*   tokslot = (int*)(ws + 80 * 1024);       // 4096
    unsigned short* Xe  = (unsigned short*)(ws + (1ull << 20));     // 16 MB
    unsigned short* hid = (unsigned short*)(ws + (18ull << 20));    // 46.14 MB
    float*          Osl = (float*)(ws + (64ull << 20));             // 33.55 MB

    const size_t REQ_FAST = (64ull << 20) + (size_t)NSLOT * HDIM * sizeof(float); // ~97.6 MB

    k_gate<<<dim3(TOKENS / 4), dim3(256), 0, stream>>>(x, gw, sel, wts);
    k_hist<<<dim3(1), dim3(256), 0, stream>>>(sel, cnt, offs, cursor);
    k_gather<<<dim3(TOKENS), dim3(256), 0, stream>>>(x, sel, wts, offs, cursor, rowtok, roww, tokslot, Xe);

    if (ws_size >= REQ_FAST) {
        // fast path: direct fp32 weight staging in-GEMM, no pre-conversion, no output atomics
        k_ffn1_bf<<<dim3(IDIM / BN, TOKENS / BM, NEXP), dim3(256), 0, stream>>>(Xe, w1, w3, cnt, offs, hid);
        k_ffn2_bf<<<dim3(HDIM / BN, TOKENS / BM, NEXP), dim3(256), 0, stream>>>(hid, w2, cnt, offs, roww, Osl);
        k_combine<<<dim3(TOKENS), dim3(256), 0, stream>>>(Osl, tokslot, out);
    } else {
        // fallback: original convert-at-stage path with atomics
        k_zero<<<dim3((TOKENS * HDIM / 4) / 256), dim3(256), 0, stream>>>(out);
        k_ffn1_cv<<<dim3(IDIM / BN, TOKENS / BM, NEXP), dim3(256), 0, stream>>>(Xe, w1, w3, cnt, offs, hid);
        k_ffn2_cv<<<dim3(HDIM / BN, TOKENS / BM, NEXP), dim3(256), 0, stream>>>(hid, w2, cnt, offs, rowtok, roww, out);
    }
}

// Round 4
// 1765.824 us; speedup vs baseline: 1.0567x; 1.0567x over previous
//
#include <hip/hip_runtime.h>
#include <hip/hip_bf16.h>

#define TOKENS 2048
#define HDIM   2048
#define IDIM   5632
#define NEXP   8
#define NSLOT  (TOKENS * 2)
#define BM 128
#define BN 128
#define BK 32

typedef __attribute__((ext_vector_type(8))) short bf16x8;
typedef __attribute__((ext_vector_type(4))) float f32x4;

__device__ __forceinline__ unsigned short f2bf(float f) {
    union { float f; unsigned u; } v; v.f = f;
    unsigned r = v.u + 0x7FFFu + ((v.u >> 16) & 1u);   // RNE to bf16
    return (unsigned short)(r >> 16);
}
// packed f32x2 -> bf16x2 (compiler emits v_cvt_pk_bf16_f32, RNE)
__device__ __forceinline__ unsigned pack2(float lo, float hi) {
    float2 f; f.x = lo; f.y = hi;
    __hip_bfloat162 h = __float22bfloat162_rn(f);
    union { __hip_bfloat162 h; unsigned u; } c; c.h = h;
    return c.u;
}
// load 8 contiguous fp32, convert to 8 bf16, write 16B to LDS (fragment-order chunk)
__device__ __forceinline__ void stage_b_chunk(const float* __restrict__ p, unsigned short* dst) {
    float4 lo = *(const float4*)(p);
    float4 hi = *(const float4*)(p + 4);
    uint4 v;
    v.x = pack2(lo.x, lo.y);
    v.y = pack2(lo.z, lo.w);
    v.z = pack2(hi.x, hi.y);
    v.w = pack2(hi.z, hi.w);
    *(uint4*)dst = v;
}
// async global->LDS, 16B per lane: LDS dest = wave-uniform base + lane*16
__device__ __forceinline__ void gl2lds16(const void* g, void* l) {
    __builtin_amdgcn_global_load_lds(
        (const __attribute__((address_space(1))) unsigned int*)g,
        (__attribute__((address_space(3))) unsigned int*)l,
        16, 0, 0);
}

// ---------------- K0: zero output (fallback path only) ----------------
__global__ __launch_bounds__(256) void k_zero(float* __restrict__ out) {
    int i = blockIdx.x * 256 + threadIdx.x;
    float4 z = {0.f, 0.f, 0.f, 0.f};
    ((float4*)out)[i] = z;
}

// ---------------- K-cvt: fp32 -> bf16 streaming convert ----------------
__global__ __launch_bounds__(256) void k_cvt(const float* __restrict__ src,
                                             unsigned short* __restrict__ dst,
                                             int n8) {
    int stride = gridDim.x * 256;
    for (int i = blockIdx.x * 256 + threadIdx.x; i < n8; i += stride) {
        const float4* p = (const float4*)(src + (size_t)i * 8);
        float4 a = p[0], b = p[1];
        uint4 v;
        v.x = pack2(a.x, a.y); v.y = pack2(a.z, a.w);
        v.z = pack2(b.x, b.y); v.w = pack2(b.z, b.w);
        *(uint4*)(dst + (size_t)i * 8) = v;
    }
}

// ---------------- K1: gate logits + sparsemixer routing ----------------
__global__ __launch_bounds__(256) void k_gate(const float* __restrict__ x,
                                              const float* __restrict__ gw,
                                              int* __restrict__ sel,
                                              float* __restrict__ wts) {
    int wave = threadIdx.x >> 6, lane = threadIdx.x & 63;
    int t = blockIdx.x * 4 + wave;
    const float4* xr = (const float4*)(x + (size_t)t * HDIM);
    const float4* g  = (const float4*)gw;
    float acc[NEXP];
#pragma unroll
    for (int e = 0; e < NEXP; e++) acc[e] = 0.f;
#pragma unroll
    for (int it = 0; it < HDIM / 4 / 64; ++it) {   // 8 iters
        int idx = it * 64 + lane;
        float4 xv = xr[idx];
#pragma unroll
        for (int e = 0; e < NEXP; e++) {
            float4 gv = g[e * (HDIM / 4) + idx];
            acc[e] += xv.x * gv.x + xv.y * gv.y + xv.z * gv.z + xv.w * gv.w;
        }
    }
#pragma unroll
    for (int e = 0; e < NEXP; e++) {
        float v = acc[e];
#pragma unroll
        for (int off = 32; off > 0; off >>= 1) v += __shfl_xor(v, off, 64);
        acc[e] = v;
    }
    if (lane == 0) {
        float s[NEXP];
#pragma unroll
        for (int e = 0; e < NEXP; e++) s[e] = acc[e];
        float m1 = s[0]; int i1 = 0;
#pragma unroll
        for (int e = 1; e < NEXP; e++) if (s[e] > m1) { m1 = s[e]; i1 = e; }
        float m2 = -3.0e38f; int i2 = 0;
#pragma unroll
        for (int e = 0; e < NEXP; e++) if (e != i1 && s[e] > m2) { m2 = s[e]; i2 = e; }
        float sum1 = 0.f;
#pragma unroll
        for (int e = 0; e < NEXP; e++) {
            float f = fmaxf(fabsf(s[e]), m1);
            bool masked = ((m1 - s[e]) / f) > 0.02f;
            if (!masked) sum1 += expf(s[e] - m1);
        }
        float sum2 = 0.f;
#pragma unroll
        for (int e = 0; e < NEXP; e++) {
            if (e == i1) continue;
            float f = fmaxf(fabsf(s[e]), m2);
            bool masked = ((m2 - s[e]) / f) > 0.02f;
            if (!masked) sum2 += expf(s[e] - m2);
        }
        sel[2 * t]     = i1;
        sel[2 * t + 1] = i2;
        wts[2 * t]     = 1.f / sum1;
        wts[2 * t + 1] = 1.f / sum2;
    }
}

// ---------------- K2: histogram + exclusive prefix ----------------
__global__ __launch_bounds__(256) void k_hist(const int* __restrict__ sel,
                                              int* __restrict__ cnt,
                                              int* __restrict__ offs,
                                              int* __restrict__ cursor) {
    __shared__ int c_s[NEXP];
    int tid = threadIdx.x;
    if (tid < NEXP) c_s[tid] = 0;
    __syncthreads();
    for (int i = tid; i < NSLOT; i += 256) atomicAdd(&c_s[sel[i]], 1);
    __syncthreads();
    if (tid == 0) {
        int o = 0;
        for (int e = 0; e < NEXP; e++) { cnt[e] = c_s[e]; offs[e] = o; o += c_s[e]; cursor[e] = 0; }
    }
}

// ---------------- K3: slot assignment + gather x rows to bf16 ----------------
__global__ __launch_bounds__(256) void k_gather(const float* __restrict__ x,
                                                const int* __restrict__ sel,
                                                const float* __restrict__ wts,
                                                const int* __restrict__ offs,
                                                int* __restrict__ cursor,
                                                int* __restrict__ rowtok,
                                                float* __restrict__ roww,
                                                int* __restrict__ tokslot,
                                                unsigned short* __restrict__ Xe) {
    int t = blockIdx.x;
    __shared__ int slot_s[2];
    if (threadIdx.x == 0) {
        int s0 = sel[2 * t], s1 = sel[2 * t + 1];
        int p0 = offs[s0] + atomicAdd(&cursor[s0], 1);
        int p1 = offs[s1] + atomicAdd(&cursor[s1], 1);
        rowtok[p0] = t; roww[p0] = wts[2 * t];
        rowtok[p1] = t; roww[p1] = wts[2 * t + 1];
        tokslot[2 * t] = p0; tokslot[2 * t + 1] = p1;
        slot_s[0] = p0; slot_s[1] = p1;
    }
    __syncthreads();
    int p0 = slot_s[0], p1 = slot_s[1];
    int base = threadIdx.x * 8;                     // 8 elems/thread, 2048 total
    const float* xp = x + (size_t)t * HDIM + base;
    float4 a = *(const float4*)(xp);
    float4 b = *(const float4*)(xp + 4);
    uint4 v;
    v.x = pack2(a.x, a.y); v.y = pack2(a.z, a.w);
    v.z = pack2(b.x, b.y); v.w = pack2(b.z, b.w);
    *(uint4*)(Xe + (size_t)p0 * HDIM + base) = v;
    *(uint4*)(Xe + (size_t)p1 * HDIM + base) = v;
}

// ==================== FAST PATH (bf16 weights, global_load_lds, dbuf 2-phase) ====================
// Depth-1 pipeline: stage tile t+1 (async) BEFORE computing tile t; single barrier
// per K-step drains the loads AFTER a full MFMA phase -> latency hidden.

#define FFN1_STAGE(b, k)                                           \
    do {                                                           \
        gl2lds16(aP0 + (k),  As  + (b) * 4096 + wave * 512);       \
        gl2lds16(aP1 + (k),  As  + (b) * 4096 + (wave + 4) * 512); \
        gl2lds16(b1P0 + (k), B1s + (b) * 4096 + wave * 512);       \
        gl2lds16(b1P1 + (k), B1s + (b) * 4096 + (wave + 4) * 512); \
        gl2lds16(b3P0 + (k), B3s + (b) * 4096 + wave * 512);       \
        gl2lds16(b3P1 + (k), B3s + (b) * 4096 + (wave + 4) * 512); \
    } while (0)

#define FFN1_COMPUTE(b)                                                                       \
    do {                                                                                      \
        bf16x8 af[4];                                                                         \
        _Pragma("unroll")                                                                     \
        for (int i = 0; i < 4; i++)                                                           \
            af[i] = *(const bf16x8*)&As[(b) * 4096 + ((wm * 4 + i) * 64 + lane) * 8];         \
        _Pragma("unroll")                                                                     \
        for (int j = 0; j < 4; j++) {                                                         \
            bf16x8 b1f = *(const bf16x8*)&B1s[(b) * 4096 + ((wn * 4 + j) * 64 + lane) * 8];   \
            bf16x8 b3f = *(const bf16x8*)&B3s[(b) * 4096 + ((wn * 4 + j) * 64 + lane) * 8];   \
            _Pragma("unroll")                                                                 \
            for (int i = 0; i < 4; i++) {                                                     \
                acc1[i][j] = __builtin_amdgcn_mfma_f32_16x16x32_bf16(af[i], b1f, acc1[i][j], 0, 0, 0); \
                acc3[i][j] = __builtin_amdgcn_mfma_f32_16x16x32_bf16(af[i], b3f, acc3[i][j], 0, 0, 0); \
            }                                                                                 \
        }                                                                                     \
    } while (0)

// ---------------- K4: stage-1 grouped GEMM: hid = silu(X@w1^T) * (X@w3^T) ----------------
// blockIdx.z == NEXP (optional extra slice): convert w2 fp32 -> bf16 (overlaps with GEMM)
__global__ __launch_bounds__(256, 2) void k_ffn1_bf(const unsigned short* __restrict__ Xe,
                                                    const unsigned short* __restrict__ w1b,
                                                    const unsigned short* __restrict__ w3b,
                                                    const int* __restrict__ cnt,
                                                    const int* __restrict__ offs,
                                                    unsigned short* __restrict__ hid,
                                                    const float* __restrict__ w2src,
                                                    unsigned short* __restrict__ w2dst) {
    if (blockIdx.z == NEXP) {
        // folded w2 conversion slice (only launched when w2dst is a private region)
        int nblk = gridDim.x * gridDim.y;
        int b = blockIdx.y * gridDim.x + blockIdx.x;
        int n8 = (int)((size_t)NEXP * IDIM * HDIM / 8);
        int stride = nblk * 256;
        for (int i = b * 256 + threadIdx.x; i < n8; i += stride) {
            const float4* p = (const float4*)(w2src + (size_t)i * 8);
            float4 a = p[0], bb = p[1];
            uint4 v;
            v.x = pack2(a.x, a.y);   v.y = pack2(a.z, a.w);
            v.z = pack2(bb.x, bb.y); v.w = pack2(bb.z, bb.w);
            *(uint4*)(w2dst + (size_t)i * 8) = v;
        }
        return;
    }
    int e = blockIdx.z;
    int c = cnt[e];
    int bm = blockIdx.y;
    if (bm * BM >= c) return;
    int n0 = blockIdx.x * BN;
    int row0 = offs[e] + bm * BM;
    int rows_here = c - bm * BM;
    const unsigned short* W1 = w1b + (size_t)e * IDIM * HDIM;
    const unsigned short* W3 = w3b + (size_t)e * IDIM * HDIM;

    // double-buffered fragment-order tiles: [2][8 chunks][512 shorts]
    __shared__ __align__(16) unsigned short As[2 * 4096];
    __shared__ __align__(16) unsigned short B1s[2 * 4096];
    __shared__ __align__(16) unsigned short B3s[2 * 4096];

    int tid = threadIdx.x, lane = tid & 63, wave = tid >> 6;
    int wm = wave >> 1, wn = wave & 1;
    int fr = lane & 15, kq = lane >> 4;

    f32x4 acc1[4][4], acc3[4][4];
    f32x4 z = {0.f, 0.f, 0.f, 0.f};
#pragma unroll
    for (int i = 0; i < 4; i++)
#pragma unroll
        for (int j = 0; j < 4; j++) { acc1[i][j] = z; acc3[i][j] = z; }

    int ar0 = min(row0 + wave * 16 + fr, NSLOT - 1);
    int ar1 = min(row0 + (wave + 4) * 16 + fr, NSLOT - 1);
    const unsigned short* aP0  = Xe + (size_t)ar0 * HDIM + kq * 8;
    const unsigned short* aP1  = Xe + (size_t)ar1 * HDIM + kq * 8;
    const unsigned short* b1P0 = W1 + (size_t)(n0 + wave * 16 + fr) * HDIM + kq * 8;
    const unsigned short* b1P1 = W1 + (size_t)(n0 + (wave + 4) * 16 + fr) * HDIM + kq * 8;
    const unsigned short* b3P0 = W3 + (size_t)(n0 + wave * 16 + fr) * HDIM + kq * 8;
    const unsigned short* b3P1 = W3 + (size_t)(n0 + (wave + 4) * 16 + fr) * HDIM + kq * 8;

    // prologue: fill buffer 0
    FFN1_STAGE(0, 0);
    __syncthreads();
    for (int k0 = 0; k0 < HDIM; k0 += 2 * BK) {
        // phase A: stage k0+32 into buf1, compute buf0
        if (k0 + BK < HDIM) FFN1_STAGE(1, k0 + BK);
        FFN1_COMPUTE(0);
        __syncthreads();   // drains vmcnt (buf1 loads) + ensures buf0 reads done
        // phase B: stage k0+64 into buf0, compute buf1
        if (k0 + 2 * BK < HDIM) FFN1_STAGE(0, k0 + 2 * BK);
        FFN1_COMPUTE(1);
        __syncthreads();
    }
    // epilogue: C/D layout col=lane&15, row=(lane>>4)*4+reg
    int qr = (lane >> 4) * 4, cb = lane & 15;
#pragma unroll
    for (int i = 0; i < 4; i++) {
        int rl = wm * 64 + i * 16 + qr;
#pragma unroll
        for (int v = 0; v < 4; v++) {
            int r = rl + v;
            if (r < rows_here) {
                size_t rowoff = (size_t)(row0 + r) * IDIM;
#pragma unroll
                for (int j = 0; j < 4; j++) {
                    float u1 = acc1[i][j][v], u3 = acc3[i][j][v];
                    float h = u1 * u3 / (1.f + __expf(-u1));   // silu(u1)*u3
                    hid[rowoff + n0 + wn * 64 + j * 16 + cb] = f2bf(h);
                }
            }
        }
    }
}

#define FFN2_STAGE(b, k)                                          \
    do {                                                          \
        gl2lds16(aP0 + (k), As + (b) * 4096 + wave * 512);        \
        gl2lds16(aP1 + (k), As + (b) * 4096 + (wave + 4) * 512);  \
        gl2lds16(bP0 + (k), Bs + (b) * 4096 + wave * 512);        \
        gl2lds16(bP1 + (k), Bs + (b) * 4096 + (wave + 4) * 512);  \
    } while (0)

#define FFN2_COMPUTE(b)                                                                     \
    do {                                                                                    \
        bf16x8 af[4];                                                                       \
        _Pragma("unroll")                                                                   \
        for (int i = 0; i < 4; i++)                                                         \
            af[i] = *(const bf16x8*)&As[(b) * 4096 + ((wm * 4 + i) * 64 + lane) * 8];       \
        _Pragma("unroll")                                                                   \
        for (int j = 0; j < 4; j++) {                                                       \
            bf16x8 bf = *(const bf16x8*)&Bs[(b) * 4096 + ((wn * 4 + j) * 64 + lane) * 8];   \
            _Pragma("unroll")                                                               \
            for (int i = 0; i < 4; i++)                                                     \
                acc[i][j] = __builtin_amdgcn_mfma_f32_16x16x32_bf16(af[i], bf, acc[i][j], 0, 0, 0); \
        }                                                                                   \
    } while (0)

// ---------------- K5: stage-2 grouped GEMM: Oslot = w * (hid @ w2^T), no atomics ----------------
__global__ __launch_bounds__(256, 2) void k_ffn2_bf(const unsigned short* __restrict__ hid,
                                                    const unsigned short* __restrict__ w2b,
                                                    const int* __restrict__ cnt,
                                                    const int* __restrict__ offs,
                                                    const float* __restrict__ roww,
                                                    float* __restrict__ Oslot) {
    int e = blockIdx.z;
    int c = cnt[e];
    int bm = blockIdx.y;
    if (bm * BM >= c) return;
    int n0 = blockIdx.x * BN;
    int row0 = offs[e] + bm * BM;
    int rows_here = c - bm * BM;
    const unsigned short* W2 = w2b + (size_t)e * HDIM * IDIM;

    __shared__ __align__(16) unsigned short As[2 * 4096];
    __shared__ __align__(16) unsigned short Bs[2 * 4096];
    __shared__ float w_s[BM];

    int tid = threadIdx.x, lane = tid & 63, wave = tid >> 6;
    int wm = wave >> 1, wn = wave & 1;
    int fr = lane & 15, kq = lane >> 4;

    if (tid < BM) w_s[tid] = (tid < rows_here) ? roww[row0 + tid] : 0.f;

    f32x4 acc[4][4];
    f32x4 z = {0.f, 0.f, 0.f, 0.f};
#pragma unroll
    for (int i = 0; i < 4; i++)
#pragma unroll
        for (int j = 0; j < 4; j++) acc[i][j] = z;

    int ar0 = min(row0 + wave * 16 + fr, NSLOT - 1);
    int ar1 = min(row0 + (wave + 4) * 16 + fr, NSLOT - 1);
    const unsigned short* aP0 = hid + (size_t)ar0 * IDIM + kq * 8;
    const unsigned short* aP1 = hid + (size_t)ar1 * IDIM + kq * 8;
    const unsigned short* bP0 = W2 + (size_t)(n0 + wave * 16 + fr) * IDIM + kq * 8;
    const unsigned short* bP1 = W2 + (size_t)(n0 + (wave + 4) * 16 + fr) * IDIM + kq * 8;

    FFN2_STAGE(0, 0);
    __syncthreads();
    for (int k0 = 0; k0 < IDIM; k0 += 2 * BK) {
        if (k0 + BK < IDIM) FFN2_STAGE(1, k0 + BK);
        FFN2_COMPUTE(0);
        __syncthreads();
        if (k0 + 2 * BK < IDIM) FFN2_STAGE(0, k0 + 2 * BK);
        FFN2_COMPUTE(1);
        __syncthreads();
    }
    int qr = (lane >> 4) * 4, cb = lane & 15;
#pragma unroll
    for (int i = 0; i < 4; i++) {
        int rl = wm * 64 + i * 16 + qr;
#pragma unroll
        for (int v = 0; v < 4; v++) {
            int r = rl + v;
            if (r < rows_here) {
                float wgt = w_s[r];
                float* orow = Oslot + (size_t)(row0 + r) * HDIM + n0 + wn * 64 + cb;
#pragma unroll
                for (int j = 0; j < 4; j++)
                    orow[j * 16] = acc[i][j][v] * wgt;
            }
        }
    }
}

// ---------------- K6: combine the two expert rows per token ----------------
__global__ __launch_bounds__(256) void k_combine(const float* __restrict__ Oslot,
                                                 const int* __restrict__ tokslot,
                                                 float* __restrict__ out) {
    int t = blockIdx.x;
    int p0 = tokslot[2 * t], p1 = tokslot[2 * t + 1];
    int i = threadIdx.x * 8;
    const float4* r0 = (const float4*)(Oslot + (size_t)p0 * HDIM + i);
    const float4* r1 = (const float4*)(Oslot + (size_t)p1 * HDIM + i);
    float4 a0 = r0[0], b0 = r0[1], a1 = r1[0], b1 = r1[1];
    float4 o0 = {a0.x + a1.x, a0.y + a1.y, a0.z + a1.z, a0.w + a1.w};
    float4 o1 = {b0.x + b1.x, b0.y + b1.y, b0.z + b1.z, b0.w + b1.w};
    float* op = out + (size_t)t * HDIM + i;
    *(float4*)op = o0;
    *(float4*)(op + 4) = o1;
}

// ==================== FALLBACK PATH (fp32 weights, convert-at-stage, BK=32) ====================

__global__ __launch_bounds__(256, 2) void k_ffn1_cv(const unsigned short* __restrict__ Xe,
                                                    const float* __restrict__ w1,
                                                    const float* __restrict__ w3,
                                                    const int* __restrict__ cnt,
                                                    const int* __restrict__ offs,
                                                    unsigned short* __restrict__ hid) {
    int e = blockIdx.z;
    int c = cnt[e];
    int bm = blockIdx.y;
    if (bm * BM >= c) return;
    int n0 = blockIdx.x * BN;
    int row0 = offs[e] + bm * BM;
    int rows_here = c - bm * BM;
    const float* W1 = w1 + (size_t)e * IDIM * HDIM;
    const float* W3 = w3 + (size_t)e * IDIM * HDIM;

    __shared__ __align__(16) unsigned short As[8 * 512];
    __shared__ __align__(16) unsigned short B1s[8 * 512];
    __shared__ __align__(16) unsigned short B3s[8 * 512];

    int tid = threadIdx.x, lane = tid & 63, wave = tid >> 6;
    int wm = wave >> 1, wn = wave & 1;
    int fr = lane & 15, kq = lane >> 4;

    f32x4 acc1[4][4], acc3[4][4];
    f32x4 z = {0.f, 0.f, 0.f, 0.f};
#pragma unroll
    for (int i = 0; i < 4; i++)
#pragma unroll
        for (int j = 0; j < 4; j++) { acc1[i][j] = z; acc3[i][j] = z; }

    int ar0 = min(row0 + wave * 16 + fr, NSLOT - 1);
    int ar1 = min(row0 + (wave + 4) * 16 + fr, NSLOT - 1);
    const unsigned short* aP0 = Xe + (size_t)ar0 * HDIM + kq * 8;
    const unsigned short* aP1 = Xe + (size_t)ar1 * HDIM + kq * 8;
    const float* b1P0 = W1 + (size_t)(n0 + wave * 16 + fr) * HDIM + kq * 8;
    const float* b1P1 = W1 + (size_t)(n0 + (wave + 4) * 16 + fr) * HDIM + kq * 8;
    const float* b3P0 = W3 + (size_t)(n0 + wave * 16 + fr) * HDIM + kq * 8;
    const float* b3P1 = W3 + (size_t)(n0 + (wave + 4) * 16 + fr) * HDIM + kq * 8;

    for (int k0 = 0; k0 < HDIM; k0 += BK) {
        __syncthreads();
        *(uint4*)&As[(size_t)tid * 8]         = *(const uint4*)(aP0 + k0);
        *(uint4*)&As[(size_t)(tid + 256) * 8] = *(const uint4*)(aP1 + k0);
        stage_b_chunk(b1P0 + k0, &B1s[(size_t)tid * 8]);
        stage_b_chunk(b1P1 + k0, &B1s[(size_t)(tid + 256) * 8]);
        stage_b_chunk(b3P0 + k0, &B3s[(size_t)tid * 8]);
        stage_b_chunk(b3P1 + k0, &B3s[(size_t)(tid + 256) * 8]);
        __syncthreads();
        bf16x8 af[4];
#pragma unroll
        for (int i = 0; i < 4; i++)
            af[i] = *(const bf16x8*)&As[((wm * 4 + i) * 64 + lane) * 8];
#pragma unroll
        for (int j = 0; j < 4; j++) {
            bf16x8 b1f = *(const bf16x8*)&B1s[((wn * 4 + j) * 64 + lane) * 8];
            bf16x8 b3f = *(const bf16x8*)&B3s[((wn * 4 + j) * 64 + lane) * 8];
#pragma unroll
            for (int i = 0; i < 4; i++) {
                acc1[i][j] = __builtin_amdgcn_mfma_f32_16x16x32_bf16(af[i], b1f, acc1[i][j], 0, 0, 0);
                acc3[i][j] = __builtin_amdgcn_mfma_f32_16x16x32_bf16(af[i], b3f, acc3[i][j], 0, 0, 0);
            }
        }
    }
    int qr = (lane >> 4) * 4, cb = lane & 15;
#pragma unroll
    for (int i = 0; i < 4; i++) {
        int rl = wm * 64 + i * 16 + qr;
#pragma unroll
        for (int v = 0; v < 4; v++) {
            int r = rl + v;
            if (r < rows_here) {
                size_t rowoff = (size_t)(row0 + r) * IDIM;
#pragma unroll
                for (int j = 0; j < 4; j++) {
                    float u1 = acc1[i][j][v], u3 = acc3[i][j][v];
                    float h = u1 * u3 / (1.f + __expf(-u1));
                    hid[rowoff + n0 + wn * 64 + j * 16 + cb] = f2bf(h);
                }
            }
        }
    }
}

__global__ __launch_bounds__(256, 2) void k_ffn2_cv(const unsigned short* __restrict__ hid,
                                                    const float* __restrict__ w2,
                                                    const int* __restrict__ cnt,
                                                    const int* __restrict__ offs,
                                                    const int* __restrict__ rowtok,
                                                    const float* __restrict__ roww,
                                                    float* __restrict__ out) {
    int e = blockIdx.z;
    int c = cnt[e];
    int bm = blockIdx.y;
    if (bm * BM >= c) return;
    int n0 = blockIdx.x * BN;
    int row0 = offs[e] + bm * BM;
    int rows_here = c - bm * BM;
    const float* W2 = w2 + (size_t)e * HDIM * IDIM;

    __shared__ __align__(16) unsigned short As[8 * 512];
    __shared__ __align__(16) unsigned short Bs[8 * 512];
    __shared__ int   tok_s[BM];
    __shared__ float w_s[BM];

    int tid = threadIdx.x, lane = tid & 63, wave = tid >> 6;
    int wm = wave >> 1, wn = wave & 1;
    int fr = lane & 15, kq = lane >> 4;

    if (tid < BM) {
        bool valid = (tid < rows_here);
        tok_s[tid] = valid ? rowtok[row0 + tid] : 0;
        w_s[tid]   = valid ? roww[row0 + tid] : 0.f;
    }

    f32x4 acc[4][4];
    f32x4 z = {0.f, 0.f, 0.f, 0.f};
#pragma unroll
    for (int i = 0; i < 4; i++)
#pragma unroll
        for (int j = 0; j < 4; j++) acc[i][j] = z;

    int ar0 = min(row0 + wave * 16 + fr, NSLOT - 1);
    int ar1 = min(row0 + (wave + 4) * 16 + fr, NSLOT - 1);
    const unsigned short* aP0 = hid + (size_t)ar0 * IDIM + kq * 8;
    const unsigned short* aP1 = hid + (size_t)ar1 * IDIM + kq * 8;
    const float* bP0 = W2 + (size_t)(n0 + wave * 16 + fr) * IDIM + kq * 8;
    const float* bP1 = W2 + (size_t)(n0 + (wave + 4) * 16 + fr) * IDIM + kq * 8;

    for (int k0 = 0; k0 < IDIM; k0 += BK) {
        __syncthreads();
        *(uint4*)&As[(size_t)tid * 8]         = *(const uint4*)(aP0 + k0);
        *(uint4*)&As[(size_t)(tid + 256) * 8] = *(const uint4*)(aP1 + k0);
        stage_b_chunk(bP0 + k0, &Bs[(size_t)tid * 8]);
        stage_b_chunk(bP1 + k0, &Bs[(size_t)(tid + 256) * 8]);
        __syncthreads();
        bf16x8 af[4];
#pragma unroll
        for (int i = 0; i < 4; i++)
            af[i] = *(const bf16x8*)&As[((wm * 4 + i) * 64 + lane) * 8];
#pragma unroll
        for (int j = 0; j < 4; j++) {
            bf16x8 bf = *(const bf16x8*)&Bs[((wn * 4 + j) * 64 + lane) * 8];
#pragma unroll
            for (int i = 0; i < 4; i++)
                acc[i][j] = __builtin_amdgcn_mfma_f32_16x16x32_bf16(af[i], bf, acc[i][j], 0, 0, 0);
        }
    }
    int qr = (lane >> 4) * 4, cb = lane & 15;
#pragma unroll
    for (int i = 0; i < 4; i++) {
        int rl = wm * 64 + i * 16 + qr;
#pragma unroll
        for (int v = 0; v < 4; v++) {
            int r = rl + v;
            if (r < rows_here) {
                int tok = tok_s[r];
                float wgt = w_s[r];
                float* orow = out + (size_t)tok * HDIM + n0 + wn * 64 + cb;
#pragma unroll
                for (int j = 0; j < 4; j++)
                    atomicAdd(orow + j * 16, acc[i][j][v] * wgt);
            }
        }
    }
}

extern "C" void kernel_launch(void* const* d_in, const int* in_sizes, int n_in,
                              void* d_out, int out_size, void* d_ws, size_t ws_size,
                              hipStream_t stream) {
    const float* x  = (const float*)d_in[0];
    const float* gw = (const float*)d_in[1];
    const float* w1 = (const float*)d_in[2];
    const float* w2 = (const float*)d_in[3];
    const float* w3 = (const float*)d_in[4];
    float* out = (float*)d_out;

    char* ws = (char*)d_ws;
    int*   sel     = (int*)(ws);                   // 4096 ints
    float* wts     = (float*)(ws + 16 * 1024);     // 4096 floats
    int*   cnt     = (int*)(ws + 32 * 1024);       // 8
    int*   offs    = (int*)(ws + 32 * 1024 + 256); // 8
    int*   cursor  = (int*)(ws + 32 * 1024 + 512); // 8
    int*   rowtok  = (int*)(ws + 48 * 1024);       // 4096
    float* roww    = (float*)(ws + 64 * 1024);     // 4096
    int*   tokslot = (int*)(ws + 80 * 1024);       // 4096
    unsigned short* Xe  = (unsigned short*)(ws + (1ull << 20));     // 16 MB
    unsigned short* hid = (unsigned short*)(ws + (18ull << 20));    // 46.14 MB
    float*          Osl = (float*)(ws + (64ull << 20));             // 33.55 MB
    unsigned short* w1b = (unsigned short*)(ws + (100ull << 20));   // 184.55 MB (ends ~284.6)
    unsigned short* w3b = (unsigned short*)(ws + (290ull << 20));   // 184.55 MB (ends ~474.6)
    unsigned short* w2sep = (unsigned short*)(ws + (480ull << 20)); // 184.55 MB (ends ~664.6)

    const size_t EIH  = (size_t)NEXP * IDIM * HDIM;          // 92,274,688 elems
    const size_t REQ1 = (290ull << 20) + EIH * 2;            // ~489 MB : aliased layout
    const size_t REQ2 = (480ull << 20) + EIH * 2;            // ~656 MB : private w2b, folded cvt

    k_gate<<<dim3(TOKENS / 4), dim3(256), 0, stream>>>(x, gw, sel, wts);
    k_hist<<<dim3(1), dim3(256), 0, stream>>>(sel, cnt, offs, cursor);
    k_gather<<<dim3(TOKENS), dim3(256), 0, stream>>>(x, sel, wts, offs, cursor, rowtok, roww, tokslot, Xe);

    if (ws_size >= REQ1) {
        bool sep = (ws_size >= REQ2);
        unsigned short* w2b = sep ? w2sep : w1b;   // aliased only when w2 cvt runs as its own kernel

        k_cvt<<<dim3(2048), dim3(256), 0, stream>>>(w1, w1b, (int)(EIH / 8));
        k_cvt<<<dim3(2048), dim3(256), 0, stream>>>(w3, w3b, (int)(EIH / 8));
        if (sep) {
            // w2 conversion folded into the GEMM launch as an extra z-slice (overlaps compute)
            k_ffn1_bf<<<dim3(IDIM / BN, TOKENS / BM, NEXP + 1), dim3(256), 0, stream>>>(
                Xe, w1b, w3b, cnt, offs, hid, w2, w2b);
        } else {
            k_ffn1_bf<<<dim3(IDIM / BN, TOKENS / BM, NEXP), dim3(256), 0, stream>>>(
                Xe, w1b, w3b, cnt, offs, hid, nullptr, nullptr);
            k_cvt<<<dim3(2048), dim3(256), 0, stream>>>(w2, w2b, (int)(EIH / 8));
        }
        k_ffn2_bf<<<dim3(HDIM / BN, TOKENS / BM, NEXP), dim3(256), 0, stream>>>(hid, w2b, cnt, offs, roww, Osl);
        k_combine<<<dim3(TOKENS), dim3(256), 0, stream>>>(Osl, tokslot, out);
    } else {
        // fallback: original convert-at-stage path with atomics
        k_zero<<<dim3((TOKENS * HDIM / 4) / 256), dim3(256), 0, stream>>>(out);
        k_ffn1_cv<<<dim3(IDIM / BN, TOKENS / BM, NEXP), dim3(256), 0, stream>>>(Xe, w1, w3, cnt, offs, hid);
        k_ffn2_cv<<<dim3(HDIM / BN, TOKENS / BM, NEXP), dim3(256), 0, stream>>>(hid, w2, cnt, offs, rowtok, roww, out);
    }
}